// Round 8
// baseline (188.996 us; speedup 1.0000x reference)
//
#include <hip/hip_runtime.h>

// EoMT criterion v7: LDS-staged GEMM k_main (coalesced HBM -> swizzled LDS ->
// MFMA fragments), cross-wave reduce in-block, small k_reduce, fused
// cost/Hungarian/losses. Shapes fixed: bs=2, N=100, C+1=7, HW=512^2, M=20.

typedef unsigned int u32;
typedef __attribute__((ext_vector_type(8))) short short8;    // 8 bf16 (4 VGPRs)
typedef __attribute__((ext_vector_type(4))) float f32x4;
typedef __attribute__((ext_vector_type(16))) float f32x16;

#define BS 2
#define NQ 100
#define C1 7
#define HWPX 262144
#define MG 20
#define NO_OBJ_C 6
#define NR2 128              // 4 row-tiles of 32; rows 100..127 pad (row 100: A=1 -> ysum)
#define NTL 4
#define CH 256               // pixels per chunk (staged at once)
#define CGRP 4               // chunks per block
#define NCG (HWPX / (CH * CGRP))   // 256 chunk-groups
#define SUB 32               // k_reduce sub-blocks per (b,rt)
#define PIECES (NCG / SUB)   // 8

// ---- workspace layout (bytes); harness ws ~838MB ----
static constexpr size_t OFF_PACKED = 0;                                   // u32 [BS][HWPX] = 2MB
static constexpr size_t OFF_P      = (size_t)BS * HWPX * 4;               // f32 [BS][NTL][NCG][2048] = 16MB
static constexpr size_t SZ_P       = (size_t)BS * NTL * NCG * 2048 * 4;
static constexpr size_t OFF_PLQ    = OFF_P + SZ_P;                        // f32 [BS][NTL][NCG][32] = 256KB
static constexpr size_t SZ_PLQ     = (size_t)BS * NTL * NCG * 32 * 4;
static constexpr size_t OFF_X      = OFF_PLQ + SZ_PLQ;                    // f32 [BS][128][32]
static constexpr size_t OFF_S      = OFF_X + (size_t)BS * NR2 * 32 * 4;
static constexpr size_t OFF_LQS    = OFF_S + (size_t)BS * NR2 * 32 * 4;   // f32 [BS][128]
static constexpr size_t ZERO_BYTES = (OFF_LQS + (size_t)BS * NR2 * 4) - OFF_X;  // 66560

__device__ __forceinline__ float fast_rcp(float x){
#if __has_builtin(__builtin_amdgcn_rcpf)
    return __builtin_amdgcn_rcpf(x);
#else
    return 1.0f / x;
#endif
}

__device__ __forceinline__ short8 mk8_4(u32 a, u32 b, u32 c, u32 d){
    union { u32 u[4]; short8 v; } t;
    t.u[0] = a; t.u[1] = b; t.u[2] = c; t.u[3] = d;
    return t.v;
}

// truncation pack: two f32 -> u32 of 2 bf16 (bias tiny vs 0.17 threshold; r7-validated)
__device__ __forceinline__ u32 pkt(float lo, float hi){
    u32 ul = __builtin_bit_cast(u32, lo), uh = __builtin_bit_cast(u32, hi);
    return (uh & 0xFFFF0000u) | (ul >> 16);
}

// ---- pack 20 binary masks into one u32 per pixel + zero accum/out ----
__global__ __launch_bounds__(256) void k_pack(const int* __restrict__ gt, u32* __restrict__ packed,
                                              float* __restrict__ accum, float* __restrict__ out){
    if (blockIdx.x == 0){
        f32x4 z = {0.f, 0.f, 0.f, 0.f};
        f32x4* a4 = (f32x4*)accum;
        for (int i = threadIdx.x; i < (int)(ZERO_BYTES / 16); i += 256) a4[i] = z;
        if (threadIdx.x < 4) out[threadIdx.x] = 0.0f;
    }
    int i4 = blockIdx.x * 256 + threadIdx.x;      // 0 .. BS*HWPX/4-1
    int base = i4 * 4;
    int b = base >> 18;
    int pix = base & (HWPX - 1);
    const int* g = gt + ((size_t)b * MG << 18) + pix;
    u32 w0 = 0, w1 = 0, w2 = 0, w3 = 0;
#pragma unroll
    for (int m = 0; m < MG; m++){
        int4 v = *(const int4*)(g + ((size_t)m << 18));
        w0 |= ((u32)v.x & 1u) << m;
        w1 |= ((u32)v.y & 1u) << m;
        w2 |= ((u32)v.z & 1u) << m;
        w3 |= ((u32)v.w & 1u) << m;
    }
    *(uint4*)(packed + ((size_t)b << 18) + pix) = make_uint4(w0, w1, w2, w3);
}

// ---- heavy kernel: stage 32 rows x 256 px into swizzled LDS, MFMA from LDS ----
__global__ __launch_bounds__(256) void k_main(const float* __restrict__ mlog, const u32* __restrict__ pkd,
                                              float* __restrict__ Ppart, float* __restrict__ Plq){
    // smem: xls u32[32*128] | pls u32[32*128] | pk u32[256]  (33 KB); reduce overlay 24KB
    __shared__ u32 smem[32*128*2 + 256];
    u32* xls = smem;
    u32* pls = smem + 32*128;
    u32* pkl = smem + 32*128*2;

    int g = blockIdx.x;                   // [BS * NTL * NCG] = 2048
    int cg = g % NCG;
    int rt = (g / NCG) % NTL;
    int b  = g / (NCG * NTL);
    int t = threadIdx.x;
    int wave = t >> 6, lane = t & 63;
    int r = lane & 31, kq = lane >> 5;

    // stage-role constants
    int srow = t >> 3;                    // 0..31 (row within tile)
    int grow = rt * 32 + srow;
    bool pad = grow >= NQ;
    const float* xr0 = mlog + ((size_t)b * NQ + (pad ? 0 : grow)) * HWPX;
    int c4 = (t & 7) * 4;                 // px sub-offset
    u32 swz = (u32)((srow & 7) << 2);
    int wbase = srow * 128;

    // B column constants: col<20 -> mask bit col; col 20 -> ones (psum); col>20 -> 0
    int c = lane & 31;
    u32 shc  = (c < MG) ? (u32)c : 0u;
    u32 andm = (c < MG) ? 1u : 0u;
    u32 orm  = (c == MG) ? 1u : 0u;

    f32x16 accX = {0,0,0,0,0,0,0,0,0,0,0,0,0,0,0,0};
    f32x16 accS = {0,0,0,0,0,0,0,0,0,0,0,0,0,0,0,0};
    float lqa = 0.0f;

    for (int it = 0; it < CGRP; ++it){
        int chunk = cg * CGRP + it;
        // ---- stage phase (coalesced global -> swizzled LDS) ----
        pkl[t] = pkd[((size_t)b << 18) + chunk * CH + t];
        const float* xr = xr0 + chunk * CH;
#pragma unroll
        for (int j = 0; j < 8; j++){
            int px = c4 + j * 32;
            u32 widx = (u32)(wbase + (px >> 1)) ^ swz;
            if (!pad){
                f32x4 xv = *(const f32x4*)(xr + px);
                float e0=__expf(-xv[0]), e1=__expf(-xv[1]), e2=__expf(-xv[2]), e3=__expf(-xv[3]);
                float d0=1.f+e0, d1=1.f+e1, d2=1.f+e2, d3=1.f+e3;
                float p0=fast_rcp(d0), p1=fast_rcp(d1), p2=fast_rcp(d2), p3=fast_rcp(d3);
                lqa -= __logf((d0*d1)*(d2*d3)) + ((xv[0]+xv[1])+(xv[2]+xv[3]));
                *(uint2*)&xls[widx] = make_uint2(pkt(xv[0],xv[1]), pkt(xv[2],xv[3]));
                *(uint2*)&pls[widx] = make_uint2(pkt(p0,p1), pkt(p2,p3));
            } else {
                *(uint2*)&xls[widx] = make_uint2(0x3F803F80u, 0x3F803F80u);
                *(uint2*)&pls[widx] = make_uint2(0x3F803F80u, 0x3F803F80u);
            }
        }
        __syncthreads();
        // ---- MFMA phase: wave w covers px [w*64, w*64+64) ----
#pragma unroll
        for (int s = 0; s < 4; s++){
            int px0 = wave * 64 + s * 16 + kq * 8;          // within chunk
            u32 ridx = (u32)(r * 128 + (px0 >> 1)) ^ ((u32)((r & 7) << 2));
            uint4 xa = *(const uint4*)&xls[ridx];
            uint4 pa = *(const uint4*)&pls[ridx];
            uint4 WA = *(const uint4*)&pkl[px0];
            uint4 WB = *(const uint4*)&pkl[px0 + 4];
            u32 b0 = (((WA.x >> shc) & andm) | orm | ((((WA.y >> shc) & andm) | orm) << 16)) * 0x3F80u;
            u32 b1 = (((WA.z >> shc) & andm) | orm | ((((WA.w >> shc) & andm) | orm) << 16)) * 0x3F80u;
            u32 b2 = (((WB.x >> shc) & andm) | orm | ((((WB.y >> shc) & andm) | orm) << 16)) * 0x3F80u;
            u32 b3 = (((WB.z >> shc) & andm) | orm | ((((WB.w >> shc) & andm) | orm) << 16)) * 0x3F80u;
            short8 Av = mk8_4(xa.x, xa.y, xa.z, xa.w);
            short8 Qv = mk8_4(pa.x, pa.y, pa.z, pa.w);
            short8 Bv = mk8_4(b0, b1, b2, b3);
            accX = __builtin_amdgcn_mfma_f32_32x32x16_bf16(Av, Bv, accX, 0, 0, 0);
            accS = __builtin_amdgcn_mfma_f32_32x32x16_bf16(Qv, Bv, accS, 0, 0, 0);
        }
        __syncthreads();
    }

    // ---- lq: fold 8 stage-lanes per row, write per-block row sums ----
    lqa += __shfl_xor(lqa, 1);
    lqa += __shfl_xor(lqa, 2);
    lqa += __shfl_xor(lqa, 4);
    if ((t & 7) == 0) Plq[(((size_t)b * NTL + rt) * NCG + cg) * 32 + srow] = lqa;

    // ---- cross-wave acc reduce via LDS overlay (24 KB), wave0 stores piece ----
    float* red = (float*)smem;
    if (wave > 0){
        int base = (wave - 1) * 2048;
#pragma unroll
        for (int p = 0; p < 4; p++){
            f32x4 vx = { accX[4*p], accX[4*p+1], accX[4*p+2], accX[4*p+3] };
            f32x4 vs = { accS[4*p], accS[4*p+1], accS[4*p+2], accS[4*p+3] };
            *(f32x4*)&red[base + p*256 + lane*4] = vx;
            *(f32x4*)&red[base + 1024 + p*256 + lane*4] = vs;
        }
    }
    __syncthreads();
    if (wave == 0){
#pragma unroll
        for (int wv = 0; wv < 3; wv++){
#pragma unroll
            for (int p = 0; p < 4; p++){
                f32x4 vx = *(const f32x4*)&red[wv*2048 + p*256 + lane*4];
                f32x4 vs = *(const f32x4*)&red[wv*2048 + 1024 + p*256 + lane*4];
                accX[4*p]   += vx[0]; accX[4*p+1] += vx[1]; accX[4*p+2] += vx[2]; accX[4*p+3] += vx[3];
                accS[4*p]   += vs[0]; accS[4*p+1] += vs[1]; accS[4*p+2] += vs[2]; accS[4*p+3] += vs[3];
            }
        }
        size_t pb = (((size_t)b * NTL + rt) * NCG + cg) * 2048;
#pragma unroll
        for (int p = 0; p < 4; p++){
            f32x4 vx = { accX[4*p], accX[4*p+1], accX[4*p+2], accX[4*p+3] };
            f32x4 vs = { accS[4*p], accS[4*p+1], accS[4*p+2], accS[4*p+3] };
            *(f32x4*)(Ppart + pb + p*256 + lane*4) = vx;
            *(f32x4*)(Ppart + pb + 1024 + p*256 + lane*4) = vs;
        }
    }
}

// ---- reduce partials -> Xg/Sg/lqs (atomicAdd into k_pack-zeroed accum) ----
__global__ __launch_bounds__(256) void k_reduce(const float* __restrict__ P, const float* __restrict__ Plq,
                                                float* __restrict__ Xg, float* __restrict__ Sg,
                                                float* __restrict__ lqs){
    int g = blockIdx.x;                   // [BS * NTL * SUB] = 256
    int sub = g % SUB;
    int rt = (g / SUB) % NTL;
    int b = g / (SUB * NTL);
    int t = threadIdx.x;
    f32x4 ax = {0,0,0,0}, as = {0,0,0,0};
    for (int i = 0; i < PIECES; i++){
        int cg = sub * PIECES + i;
        const float* base = P + (((size_t)b * NTL + rt) * NCG + cg) * 2048;
        ax += *(const f32x4*)(base + t*4);
        as += *(const f32x4*)(base + 1024 + t*4);
    }
    // 32x32 C/D layout [m74/m101]: col=lane&31, row=(reg&3)+8*(reg>>2)+4*(lane>>5)
    int p = t >> 6, l = t & 63;
    int col = l & 31;
#pragma unroll
    for (int j = 0; j < 4; j++){
        int row32 = j + 8*p + 4*(l >> 5);
        size_t o = ((size_t)b * NR2 + rt*32 + row32) * 32 + col;
        atomicAdd(&Xg[o], ax[j]);
        atomicAdd(&Sg[o], as[j]);
    }
    if (t < 32){
        float s = 0.f;
        for (int i = 0; i < PIECES; i++){
            int cg = sub * PIECES + i;
            s += Plq[(((size_t)b * NTL + rt) * NCG + cg) * 32 + t];
        }
        atomicAdd(&lqs[b * NR2 + rt*32 + t], s);
    }
}

// ---- fused: cost matrix + Hungarian (JV, f64, faithful) + final losses ----
__global__ __launch_bounds__(64) void k_match(const float* __restrict__ cl, const int* __restrict__ gtc,
                                              const float* __restrict__ Xg, const float* __restrict__ Sg,
                                              const float* __restrict__ lqs, float* __restrict__ out){
    __shared__ double c[MG][NQ];
    __shared__ double u[MG + 1];
    __shared__ double v[NQ + 1];
    __shared__ double minv[NQ + 1];
    __shared__ int p[NQ + 1];
    __shared__ int way[NQ + 1];
    __shared__ int used[NQ + 1];
    int b = blockIdx.x, t = threadIdx.x;

    for (int q = t; q < NQ; q += 64){
        const float* lg = cl + ((size_t)b * NQ + q) * C1;
        float l0=lg[0],l1=lg[1],l2=lg[2],l3=lg[3],l4=lg[4],l5=lg[5],l6=lg[6];
        float mx = fmaxf(fmaxf(fmaxf(l0,l1),fmaxf(l2,l3)), fmaxf(fmaxf(l4,l5),l6));
        float e0=__expf(l0-mx),e1=__expf(l1-mx),e2=__expf(l2-mx),e3=__expf(l3-mx),
              e4=__expf(l4-mx),e5=__expf(l5-mx),e6=__expf(l6-mx);
        float inv = 1.0f / (e0+e1+e2+e3+e4+e5+e6);
        float lqv = lqs[b * NR2 + q];
        float psv = Sg[((size_t)b * NR2 + q) * 32 + 20];
#pragma unroll
        for (int m = 0; m < MG; m++){
            int cc = gtc[b * MG + m];
            float ec = (cc==0)?e0:(cc==1)?e1:(cc==2)?e2:(cc==3)?e3:(cc==4)?e4:e5;
            float Xv = Xg[((size_t)b * NR2 + q) * 32 + m];
            float Sv = Sg[((size_t)b * NR2 + q) * 32 + m];
            float ysm = Xg[((size_t)b * NR2 + 100) * 32 + m];
            float bce = -(Xv + lqv) * (1.0f / (float)HWPX);
            float dice = 1.0f - (2.0f * Sv + 1.0f) / (psv + ysm + 1.0f);
            c[m][q] = (double)(2.0f * (-ec * inv) + 5.0f * bce + 5.0f * dice);
        }
    }
    for (int j = t; j <= NQ; j += 64){ v[j] = 0.0; p[j] = 0; way[j] = 0; }
    if (t <= MG) u[t] = 0.0;
    __syncthreads();

    const double INF = 1e18;
    for (int i = 1; i <= MG; i++){
        if (t == 0) p[0] = i;
        for (int j = t; j <= NQ; j += 64){ minv[j] = INF; used[j] = 0; }
        __syncthreads();
        int j0 = 0;
        while (true){
            if (t == 0) used[j0] = 1;
            __syncthreads();
            int i0 = p[j0];
            double du = u[i0];
            for (int j = t + 1; j <= NQ; j += 64){
                if (!used[j]){
                    double cand = c[i0 - 1][j - 1] - du - v[j];
                    if (cand < minv[j]){ minv[j] = cand; way[j] = j0; }
                }
            }
            __syncthreads();
            double best = INF; int bj = NQ + 1;
            for (int j = t + 1; j <= NQ; j += 64){
                double mv = used[j] ? INF : minv[j];
                if (mv < best || (mv == best && j < bj)){ best = mv; bj = j; }
            }
#pragma unroll
            for (int off = 32; off; off >>= 1){
                double ob = __shfl_xor(best, off);
                int    oj = __shfl_xor(bj, off);
                if (ob < best || (ob == best && oj < bj)){ best = ob; bj = oj; }
            }
            int j1 = bj;
            double delta = best;
            for (int j = t; j <= NQ; j += 64){
                if (used[j]){ u[p[j]] += delta; v[j] -= delta; }
                else        { minv[j] -= delta; }
            }
            __syncthreads();
            j0 = j1;
            if (p[j0] == 0) break;
        }
        if (t == 0){
            int jj = j0;
            while (jj){ int jn = way[jj]; p[jj] = p[jn]; jj = jn; }
        }
        __syncthreads();
    }

    float wnll = 0.f, wsum = 0.f, bsum = 0.f, dsum = 0.f;
    for (int q = t; q < NQ; q += 64){
        int pi = p[q + 1];
        int tg = (pi != 0) ? gtc[b * MG + (pi - 1)] : NO_OBJ_C;
        const float* lg = cl + ((size_t)b * NQ + q) * C1;
        float l0=lg[0],l1=lg[1],l2=lg[2],l3=lg[3],l4=lg[4],l5=lg[5],l6=lg[6];
        float mx = fmaxf(fmaxf(fmaxf(l0,l1),fmaxf(l2,l3)), fmaxf(fmaxf(l4,l5),l6));
        float se = __expf(l0-mx)+__expf(l1-mx)+__expf(l2-mx)+__expf(l3-mx)
                 + __expf(l4-mx)+__expf(l5-mx)+__expf(l6-mx);
        float lse = __logf(se) + mx;
        float lt = (tg==0)?l0:(tg==1)?l1:(tg==2)?l2:(tg==3)?l3:(tg==4)?l4:(tg==5)?l5:l6;
        float w = (tg == NO_OBJ_C) ? 0.1f : 1.0f;
        wnll += w * (lse - lt);
        wsum += w;
        if (pi != 0){
            int k = pi - 1;
            float Xv  = Xg[((size_t)b * NR2 + q) * 32 + k];
            float Sv  = Sg[((size_t)b * NR2 + q) * 32 + k];
            float lqv = lqs[b * NR2 + q];
            float psv = Sg[((size_t)b * NR2 + q) * 32 + 20];
            float ysm = Xg[((size_t)b * NR2 + 100) * 32 + k];
            bsum += -(Xv + lqv);
            dsum += 1.0f - (2.0f * Sv + 1.0f) / (psv + ysm + 1.0f);
        }
    }
#pragma unroll
    for (int off = 32; off; off >>= 1){
        wnll += __shfl_xor(wnll, off);
        wsum += __shfl_xor(wsum, off);
        bsum += __shfl_xor(bsum, off);
        dsum += __shfl_xor(dsum, off);
    }
    if (t == 0){
        float tc = wnll / wsum;
        float tm = bsum / ((float)MG * (float)HWPX);
        float td = dsum / (float)MG;
        atomicAdd(&out[0], 0.5f * tc);
        atomicAdd(&out[1], 0.5f * tm);
        atomicAdd(&out[2], 0.5f * td);
        atomicAdd(&out[3], 0.5f * (2.0f * tc + 5.0f * tm + 5.0f * td));
    }
}

extern "C" void kernel_launch(void* const* d_in, const int* in_sizes, int n_in,
                              void* d_out, int out_size, void* d_ws, size_t ws_size,
                              hipStream_t stream){
    const float* cls_logits  = (const float*)d_in[0];
    const float* mask_logits = (const float*)d_in[1];
    const int*   gt_classes  = (const int*)d_in[2];
    const int*   gt_masks    = (const int*)d_in[3];
    float* out = (float*)d_out;
    char* ws = (char*)d_ws;

    u32*   packed = (u32*)  (ws + OFF_PACKED);
    float* Ppart  = (float*)(ws + OFF_P);
    float* Plq    = (float*)(ws + OFF_PLQ);
    float* Xg     = (float*)(ws + OFF_X);
    float* Sg     = (float*)(ws + OFF_S);
    float* lqs    = (float*)(ws + OFF_LQS);

    hipLaunchKernelGGL(k_pack,   dim3(BS * HWPX / 1024),  dim3(256), 0, stream, gt_masks, packed, Xg, out);
    hipLaunchKernelGGL(k_main,   dim3(BS * NTL * NCG),    dim3(256), 0, stream, mask_logits, packed, Ppart, Plq);
    hipLaunchKernelGGL(k_reduce, dim3(BS * NTL * SUB),    dim3(256), 0, stream, Ppart, Plq, Xg, Sg, lqs);
    hipLaunchKernelGGL(k_match,  dim3(BS),                dim3(64),  0, stream, cls_logits, gt_classes, Xg, Sg, lqs, out);
}

// Round 9
// 163.512 us; speedup vs baseline: 1.1559x; 1.1559x over previous
//
#include <hip/hip_runtime.h>

// EoMT criterion v8: barrier-free register-pipeline k_main (32x32x16 MFMA,
// 3-deep explicit prefetch, 16 waves/CU), bf16-packed partials, parallel
// reduce, fused cost/Hungarian/losses. bs=2, N=100, C+1=7, HW=512^2, M=20.

typedef unsigned int u32;
typedef __attribute__((ext_vector_type(8))) short short8;    // 8 bf16 (4 VGPRs)
typedef __attribute__((ext_vector_type(4))) float f32x4;
typedef __attribute__((ext_vector_type(16))) float f32x16;

#define BS 2
#define NQ 100
#define C1 7
#define HWPX 262144
#define MG 20
#define NO_OBJ_C 6
#define NR2 128              // 4 tiles of 32 rows; rows 100..127 pad (row 100: A=1 -> ysum)
#define NTL 4
#define CH 256               // pixels per block
#define NCH (HWPX / CH)      // 1024
#define KST (CH / 16)        // 16 k-steps (K=16 per MFMA)
#define PF 3                 // prefetch depth
#define RSUB 64              // k_reduce sub-blocks per (b,tile)
#define RCH (NCH / RSUB)     // 16 chunks per reduce block

// ---- workspace layout (bytes); harness ws ~838MB ----
static constexpr size_t OFF_PACKED = 0;                                   // u32 [BS][HWPX] = 2MB
static constexpr size_t OFF_P      = (size_t)BS * HWPX * 4;               // u32 [BS][NCH][NTL][1024] = 32MB (bf16-packed)
static constexpr size_t SZ_P       = (size_t)BS * NCH * NTL * 1024 * 4;
static constexpr size_t OFF_PLQ    = OFF_P + SZ_P;                        // f32 [BS][NCH][NTL][32] = 1MB
static constexpr size_t SZ_PLQ     = (size_t)BS * NCH * NTL * 32 * 4;
static constexpr size_t OFF_X      = OFF_PLQ + SZ_PLQ;                    // f32 [BS][128][32]
static constexpr size_t OFF_S      = OFF_X + (size_t)BS * NR2 * 32 * 4;
static constexpr size_t OFF_LQS    = OFF_S + (size_t)BS * NR2 * 32 * 4;   // f32 [BS][128]
static constexpr size_t ZERO_BYTES = (OFF_LQS + (size_t)BS * NR2 * 4) - OFF_X;  // 66560

__device__ __forceinline__ float fast_rcp(float x){
#if __has_builtin(__builtin_amdgcn_rcpf)
    return __builtin_amdgcn_rcpf(x);
#else
    return 1.0f / x;
#endif
}

__device__ __forceinline__ short8 mk8_4(u32 a, u32 b, u32 c, u32 d){
    union { u32 u[4]; short8 v; } t;
    t.u[0] = a; t.u[1] = b; t.u[2] = c; t.u[3] = d;
    return t.v;
}

// truncation pack: two f32 -> u32 of 2 bf16 (bias tiny vs 0.17 threshold; r7/r8-validated)
__device__ __forceinline__ u32 pkt(float lo, float hi){
    u32 ul = __builtin_bit_cast(u32, lo), uh = __builtin_bit_cast(u32, hi);
    return (uh & 0xFFFF0000u) | (ul >> 16);
}
__device__ __forceinline__ float bflo(u32 u){ return __builtin_bit_cast(float, u << 16); }
__device__ __forceinline__ float bfhi(u32 u){ return __builtin_bit_cast(float, u & 0xFFFF0000u); }

// ---- pack 20 binary masks into one u32 per pixel + zero accum/out ----
__global__ __launch_bounds__(256) void k_pack(const int* __restrict__ gt, u32* __restrict__ packed,
                                              float* __restrict__ accum, float* __restrict__ out){
    if (blockIdx.x == 0){
        f32x4 z = {0.f, 0.f, 0.f, 0.f};
        f32x4* a4 = (f32x4*)accum;
        for (int i = threadIdx.x; i < (int)(ZERO_BYTES / 16); i += 256) a4[i] = z;
        if (threadIdx.x < 4) out[threadIdx.x] = 0.0f;
    }
    int i4 = blockIdx.x * 256 + threadIdx.x;      // 0 .. BS*HWPX/4-1
    int base = i4 * 4;
    int b = base >> 18;
    int pix = base & (HWPX - 1);
    const int* g = gt + ((size_t)b * MG << 18) + pix;
    u32 w0 = 0, w1 = 0, w2 = 0, w3 = 0;
#pragma unroll
    for (int m = 0; m < MG; m++){
        int4 v = *(const int4*)(g + ((size_t)m << 18));
        w0 |= ((u32)v.x & 1u) << m;
        w1 |= ((u32)v.y & 1u) << m;
        w2 |= ((u32)v.z & 1u) << m;
        w3 |= ((u32)v.w & 1u) << m;
    }
    *(uint4*)(packed + ((size_t)b << 18) + pix) = make_uint4(w0, w1, w2, w3);
}

// ---- heavy kernel: wave = 32-row tile; barrier-free, 3-deep prefetch ----
__global__ __launch_bounds__(256, 4) void k_main(const float* __restrict__ mlog, const u32* __restrict__ pkd,
                                                 u32* __restrict__ Ppart, float* __restrict__ Plq){
    int blk = blockIdx.x;                 // [BS * NCH] = 2048
    int chunk = blk % NCH;
    int b = blk / NCH;
    int t = threadIdx.x;
    int wave = t >> 6, lane = t & 63;
    int r = lane & 31, kq = lane >> 5;
    int row = wave * 32 + r;
    bool pad = row >= NQ;                 // pad rows read row 99 (broadcast), A forced to 1.0
    int rowc = pad ? (NQ - 1) : row;

    const float* xp = mlog + ((size_t)b * NQ + rowc) * HWPX + chunk * CH + kq * 8;
    const u32*   wp = pkd + ((size_t)b << 18) + chunk * CH + kq * 8;

    // B column constants: col<20 -> mask bit col; col 20 -> ones (psum); col>20 -> 0
    int c = lane & 31;
    u32 shc  = (c < MG) ? (u32)c : 0u;
    u32 andm = (c < MG) ? 1u : 0u;
    u32 orm  = (c == MG) ? 1u : 0u;

    f32x16 accX = {0,0,0,0,0,0,0,0,0,0,0,0,0,0,0,0};
    f32x16 accS = {0,0,0,0,0,0,0,0,0,0,0,0,0,0,0,0};
    float lqacc = 0.0f;

    auto bpair = [&](u32 wl, u32 wh) -> u32 {
        u32 bl = ((wl >> shc) & andm) | orm;
        u32 bh = ((wh >> shc) & andm) | orm;
        return (bl | (bh << 16)) * 0x3F80u;     // {0,1} -> bf16 {0,1.0} packed
    };
    auto step = [&](f32x4 XA, f32x4 XB, uint4 WA, uint4 WB){
        float x0=XA[0],x1=XA[1],x2=XA[2],x3=XA[3];
        float x4=XB[0],x5=XB[1],x6=XB[2],x7=XB[3];
        float e0=__expf(-x0),e1=__expf(-x1),e2=__expf(-x2),e3=__expf(-x3);
        float e4=__expf(-x4),e5=__expf(-x5),e6=__expf(-x6),e7=__expf(-x7);
        float d0=1.f+e0,d1=1.f+e1,d2=1.f+e2,d3=1.f+e3;
        float d4=1.f+e4,d5=1.f+e5,d6=1.f+e6,d7=1.f+e7;
        float p0=fast_rcp(d0),p1=fast_rcp(d1),p2=fast_rcp(d2),p3=fast_rcp(d3);
        float p4=fast_rcp(d4),p5=fast_rcp(d5),p6=fast_rcp(d6),p7=fast_rcp(d7);
        // sum log(1-sigmoid(x)) = -log(prod d) - sum x   (one log per 8 px)
        float pr = ((d0*d1)*(d2*d3))*((d4*d5)*(d6*d7));
        lqacc -= __logf(pr) + (((x0+x1)+(x2+x3))+((x4+x5)+(x6+x7)));
        u32 a0 = pad ? 0x3F803F80u : pkt(x0,x1);
        u32 a1 = pad ? 0x3F803F80u : pkt(x2,x3);
        u32 a2 = pad ? 0x3F803F80u : pkt(x4,x5);
        u32 a3 = pad ? 0x3F803F80u : pkt(x6,x7);
        u32 q0 = pkt(p0,p1), q1 = pkt(p2,p3), q2 = pkt(p4,p5), q3 = pkt(p6,p7);
        u32 b0 = bpair(WA.x, WA.y), b1 = bpair(WA.z, WA.w);
        u32 b2 = bpair(WB.x, WB.y), b3 = bpair(WB.z, WB.w);
        short8 Av = mk8_4(a0,a1,a2,a3);
        short8 Qv = mk8_4(q0,q1,q2,q3);
        short8 Bv = mk8_4(b0,b1,b2,b3);
        accX = __builtin_amdgcn_mfma_f32_32x32x16_bf16(Av, Bv, accX, 0, 0, 0);
        accS = __builtin_amdgcn_mfma_f32_32x32x16_bf16(Qv, Bv, accS, 0, 0, 0);
    };

    // 3-deep prefetch pipeline; full unroll makes all buffer indices static
    f32x4 xa[PF], xb[PF]; uint4 wa[PF], wb[PF];
#pragma unroll
    for (int s = 0; s < PF; ++s){
        xa[s] = *(const f32x4*)(xp + s*16);
        xb[s] = *(const f32x4*)(xp + s*16 + 4);
        wa[s] = *(const uint4*)(wp + s*16);
        wb[s] = *(const uint4*)(wp + s*16 + 4);
    }
#pragma unroll
    for (int s = 0; s < KST; ++s){
        int bi = s % PF;
        f32x4 XA = xa[bi], XB = xb[bi];
        uint4 WA = wa[bi], WB = wb[bi];
        if (s + PF < KST){
            xa[bi] = *(const f32x4*)(xp + (s+PF)*16);
            xb[bi] = *(const f32x4*)(xp + (s+PF)*16 + 4);
            wa[bi] = *(const uint4*)(wp + (s+PF)*16);
            wb[bi] = *(const uint4*)(wp + (s+PF)*16 + 4);
        }
        step(XA, XB, WA, WB);
    }

    // contention-free per-wave partial stores, bf16-packed: X[512 u32] | S[512 u32]
    size_t pb = (((size_t)b * NCH + chunk) * NTL + wave) * 1024;
#pragma unroll
    for (int p = 0; p < 4; p++){
        uint2 vx = make_uint2(pkt(accX[4*p], accX[4*p+1]), pkt(accX[4*p+2], accX[4*p+3]));
        uint2 vs = make_uint2(pkt(accS[4*p], accS[4*p+1]), pkt(accS[4*p+2], accS[4*p+3]));
        *(uint2*)(Ppart + pb + p*128 + lane*2) = vx;
        *(uint2*)(Ppart + pb + 512 + p*128 + lane*2) = vs;
    }
    lqacc += __shfl_xor(lqacc, 32);       // fold kq halves; lanes 0..31 hold row totals
    if (lane < 32) Plq[(((size_t)b * NCH + chunk) * NTL + wave) * 32 + lane] = lqacc;
}

// ---- reduce bf16 partials -> Xg/Sg/lqs (atomicAdd into k_pack-zeroed accum) ----
__global__ __launch_bounds__(256) void k_reduce(const u32* __restrict__ P, const float* __restrict__ Plq,
                                                float* __restrict__ Xg, float* __restrict__ Sg,
                                                float* __restrict__ lqs){
    int g = blockIdx.x;                   // [BS * NTL * RSUB] = 512
    int sub = g % RSUB;
    int tile = (g / RSUB) % NTL;
    int b = g / (RSUB * NTL);
    int t = threadIdx.x;
    f32x4 ax = {0,0,0,0}, as = {0,0,0,0};
    for (int i = 0; i < RCH; i++){
        int ch = sub * RCH + i;
        const u32* base = P + (((size_t)b * NCH + ch) * NTL + tile) * 1024;
        uint2 ux = *(const uint2*)(base + t*2);
        uint2 us = *(const uint2*)(base + 512 + t*2);
        ax[0] += bflo(ux.x); ax[1] += bfhi(ux.x); ax[2] += bflo(ux.y); ax[3] += bfhi(ux.y);
        as[0] += bflo(us.x); as[1] += bfhi(us.x); as[2] += bflo(us.y); as[3] += bfhi(us.y);
    }
    // 32x32 C/D layout [m74/m101]: col=lane&31, row=(reg&3)+8*(reg>>2)+4*(lane>>5)
    int p = t >> 6, l = t & 63;
    int col = l & 31;
#pragma unroll
    for (int j = 0; j < 4; j++){
        int row32 = j + 8*p + 4*(l >> 5);
        size_t o = ((size_t)b * NR2 + tile*32 + row32) * 32 + col;
        atomicAdd(&Xg[o], ax[j]);
        atomicAdd(&Sg[o], as[j]);
    }
    if (t < 32){
        float s = 0.f;
        for (int i = 0; i < RCH; i++){
            int ch = sub * RCH + i;
            s += Plq[(((size_t)b * NCH + ch) * NTL + tile) * 32 + t];
        }
        atomicAdd(&lqs[b * NR2 + tile*32 + t], s);
    }
}

// ---- fused: cost matrix + Hungarian (JV, f64, faithful) + final losses ----
__global__ __launch_bounds__(64) void k_match(const float* __restrict__ cl, const int* __restrict__ gtc,
                                              const float* __restrict__ Xg, const float* __restrict__ Sg,
                                              const float* __restrict__ lqs, float* __restrict__ out){
    __shared__ double c[MG][NQ];
    __shared__ double u[MG + 1];
    __shared__ double v[NQ + 1];
    __shared__ double minv[NQ + 1];
    __shared__ int p[NQ + 1];
    __shared__ int way[NQ + 1];
    __shared__ int used[NQ + 1];
    int b = blockIdx.x, t = threadIdx.x;

    for (int q = t; q < NQ; q += 64){
        const float* lg = cl + ((size_t)b * NQ + q) * C1;
        float l0=lg[0],l1=lg[1],l2=lg[2],l3=lg[3],l4=lg[4],l5=lg[5],l6=lg[6];
        float mx = fmaxf(fmaxf(fmaxf(l0,l1),fmaxf(l2,l3)), fmaxf(fmaxf(l4,l5),l6));
        float e0=__expf(l0-mx),e1=__expf(l1-mx),e2=__expf(l2-mx),e3=__expf(l3-mx),
              e4=__expf(l4-mx),e5=__expf(l5-mx),e6=__expf(l6-mx);
        float inv = 1.0f / (e0+e1+e2+e3+e4+e5+e6);
        float lqv = lqs[b * NR2 + q];
        float psv = Sg[((size_t)b * NR2 + q) * 32 + 20];
#pragma unroll
        for (int m = 0; m < MG; m++){
            int cc = gtc[b * MG + m];
            float ec = (cc==0)?e0:(cc==1)?e1:(cc==2)?e2:(cc==3)?e3:(cc==4)?e4:e5;
            float Xv = Xg[((size_t)b * NR2 + q) * 32 + m];
            float Sv = Sg[((size_t)b * NR2 + q) * 32 + m];
            float ysm = Xg[((size_t)b * NR2 + 100) * 32 + m];
            float bce = -(Xv + lqv) * (1.0f / (float)HWPX);
            float dice = 1.0f - (2.0f * Sv + 1.0f) / (psv + ysm + 1.0f);
            c[m][q] = (double)(2.0f * (-ec * inv) + 5.0f * bce + 5.0f * dice);
        }
    }
    for (int j = t; j <= NQ; j += 64){ v[j] = 0.0; p[j] = 0; way[j] = 0; }
    if (t <= MG) u[t] = 0.0;
    __syncthreads();

    const double INF = 1e18;
    for (int i = 1; i <= MG; i++){
        if (t == 0) p[0] = i;
        for (int j = t; j <= NQ; j += 64){ minv[j] = INF; used[j] = 0; }
        __syncthreads();
        int j0 = 0;
        while (true){
            if (t == 0) used[j0] = 1;
            __syncthreads();
            int i0 = p[j0];
            double du = u[i0];
            for (int j = t + 1; j <= NQ; j += 64){
                if (!used[j]){
                    double cand = c[i0 - 1][j - 1] - du - v[j];
                    if (cand < minv[j]){ minv[j] = cand; way[j] = j0; }
                }
            }
            __syncthreads();
            double best = INF; int bj = NQ + 1;
            for (int j = t + 1; j <= NQ; j += 64){
                double mv = used[j] ? INF : minv[j];
                if (mv < best || (mv == best && j < bj)){ best = mv; bj = j; }
            }
#pragma unroll
            for (int off = 32; off; off >>= 1){
                double ob = __shfl_xor(best, off);
                int    oj = __shfl_xor(bj, off);
                if (ob < best || (ob == best && oj < bj)){ best = ob; bj = oj; }
            }
            int j1 = bj;
            double delta = best;
            for (int j = t; j <= NQ; j += 64){
                if (used[j]){ u[p[j]] += delta; v[j] -= delta; }
                else        { minv[j] -= delta; }
            }
            __syncthreads();
            j0 = j1;
            if (p[j0] == 0) break;
        }
        if (t == 0){
            int jj = j0;
            while (jj){ int jn = way[jj]; p[jj] = p[jn]; jj = jn; }
        }
        __syncthreads();
    }

    float wnll = 0.f, wsum = 0.f, bsum = 0.f, dsum = 0.f;
    for (int q = t; q < NQ; q += 64){
        int pi = p[q + 1];
        int tg = (pi != 0) ? gtc[b * MG + (pi - 1)] : NO_OBJ_C;
        const float* lg = cl + ((size_t)b * NQ + q) * C1;
        float l0=lg[0],l1=lg[1],l2=lg[2],l3=lg[3],l4=lg[4],l5=lg[5],l6=lg[6];
        float mx = fmaxf(fmaxf(fmaxf(l0,l1),fmaxf(l2,l3)), fmaxf(fmaxf(l4,l5),l6));
        float se = __expf(l0-mx)+__expf(l1-mx)+__expf(l2-mx)+__expf(l3-mx)
                 + __expf(l4-mx)+__expf(l5-mx)+__expf(l6-mx);
        float lse = __logf(se) + mx;
        float lt = (tg==0)?l0:(tg==1)?l1:(tg==2)?l2:(tg==3)?l3:(tg==4)?l4:(tg==5)?l5:l6;
        float w = (tg == NO_OBJ_C) ? 0.1f : 1.0f;
        wnll += w * (lse - lt);
        wsum += w;
        if (pi != 0){
            int k = pi - 1;
            float Xv  = Xg[((size_t)b * NR2 + q) * 32 + k];
            float Sv  = Sg[((size_t)b * NR2 + q) * 32 + k];
            float lqv = lqs[b * NR2 + q];
            float psv = Sg[((size_t)b * NR2 + q) * 32 + 20];
            float ysm = Xg[((size_t)b * NR2 + 100) * 32 + k];
            bsum += -(Xv + lqv);
            dsum += 1.0f - (2.0f * Sv + 1.0f) / (psv + ysm + 1.0f);
        }
    }
#pragma unroll
    for (int off = 32; off; off >>= 1){
        wnll += __shfl_xor(wnll, off);
        wsum += __shfl_xor(wsum, off);
        bsum += __shfl_xor(bsum, off);
        dsum += __shfl_xor(dsum, off);
    }
    if (t == 0){
        float tc = wnll / wsum;
        float tm = bsum / ((float)MG * (float)HWPX);
        float td = dsum / (float)MG;
        atomicAdd(&out[0], 0.5f * tc);
        atomicAdd(&out[1], 0.5f * tm);
        atomicAdd(&out[2], 0.5f * td);
        atomicAdd(&out[3], 0.5f * (2.0f * tc + 5.0f * tm + 5.0f * td));
    }
}

extern "C" void kernel_launch(void* const* d_in, const int* in_sizes, int n_in,
                              void* d_out, int out_size, void* d_ws, size_t ws_size,
                              hipStream_t stream){
    const float* cls_logits  = (const float*)d_in[0];
    const float* mask_logits = (const float*)d_in[1];
    const int*   gt_classes  = (const int*)d_in[2];
    const int*   gt_masks    = (const int*)d_in[3];
    float* out = (float*)d_out;
    char* ws = (char*)d_ws;

    u32*   packed = (u32*)  (ws + OFF_PACKED);
    u32*   Ppart  = (u32*)  (ws + OFF_P);
    float* Plq    = (float*)(ws + OFF_PLQ);
    float* Xg     = (float*)(ws + OFF_X);
    float* Sg     = (float*)(ws + OFF_S);
    float* lqs    = (float*)(ws + OFF_LQS);

    hipLaunchKernelGGL(k_pack,   dim3(BS * HWPX / 1024),  dim3(256), 0, stream, gt_masks, packed, Xg, out);
    hipLaunchKernelGGL(k_main,   dim3(BS * NCH),          dim3(256), 0, stream, mask_logits, packed, Ppart, Plq);
    hipLaunchKernelGGL(k_reduce, dim3(BS * NTL * RSUB),   dim3(256), 0, stream, Ppart, Plq, Xg, Sg, lqs);
    hipLaunchKernelGGL(k_match,  dim3(BS),                dim3(64),  0, stream, cls_logits, gt_classes, Xg, Sg, lqs, out);
}